// Round 15
// baseline (145.370 us; speedup 1.0000x reference)
//
#include <hip/hip_runtime.h>
#include <hip/hip_bf16.h>
#include <math.h>

typedef __attribute__((ext_vector_type(4))) float f32x4;
typedef __attribute__((ext_vector_type(16))) float f32x16;
typedef __attribute__((ext_vector_type(8))) int i32x8;
typedef __attribute__((ext_vector_type(4))) int i32x4;

#define TEMP_INV 14.2857142857142857f     // 1/0.07
#define SCALE_EPI 0.013950892857142857f   // TEMP_INV / 1024 (32*32 prescale)
#define K2EPI 0.020126883973f             // SCALE_EPI * log2(e)
#define UNIT_SCALE 0x7f7f7f7f             // E8M0 127 -> x1.0 exact (verified)

// ---- async global->LDS, 16B per lane
static __device__ inline void async16(const void* g, void* l) {
  __builtin_amdgcn_global_load_lds(
      (const __attribute__((address_space(1))) unsigned int*)g,
      (__attribute__((address_space(3))) unsigned int*)l,
      16, 0, 0);
}

// ---- OCP fp4 e2m1 encode, branchless (R13-verified: absmax 0.031)
static __device__ inline int fp4e(float y) {
  const float af = fabsf(y);
  int code = (int)fminf(fmaf(af, 2.0f, 0.5f), 4.9f);
  code += (af > 2.5f) + (af > 3.5f) + (af > 5.0f);
  return code | ((int)(__float_as_uint(y) >> 28) & 8);
}

// ============================================================
// Fragment-major MX-fp4 format (verified R8-R14):
//   panel p = 32 rows, k-step s = 64 K-elems. record(p,s) = 1 KB at
//   (p*16+s)*1024. Lane l: row p*32+(l&31), k-elems s*64+(l>>5)*32..
//   16 B at rec + l*16. Values are 32*x (exact pow-2 prescale).
// ============================================================

// ============================================================
// Kernel 1: L2-normalize rows (D=1024) -> fp4 fragment-major.
// (R13 version, verified)
// ============================================================
__global__ __launch_bounds__(1024) void normalize_rows(
    const float* __restrict__ a, const float* __restrict__ b,
    int* __restrict__ oa, int* __restrict__ ob,
    float* __restrict__ pos_acc, float* __restrict__ neg_acc,
    float* __restrict__ dout, int N, int D) {
  __shared__ __align__(16) unsigned short sPk[8192];  // 16 KB

  const int blk = blockIdx.x;          // 0..511
  const bool isA = blk < 256;
  const int p = isA ? blk : blk - 256;
  const float* src = (isA ? a : b) + (size_t)p * 32 * D;
  int* out = isA ? oa : ob;

  const int tid = threadIdx.x;
  const int r = tid >> 5;   // row within panel
  const int c = tid & 31;   // chunk within row

  if (blk == 0 && tid == 0) dout[0] = 0.f;
  if (isA && c == 0) {
    pos_acc[p * 32 + r] = 0.f;
    neg_acc[p * 32 + r] = 0.f;
  }

  const float4* inr = (const float4*)(src + (size_t)r * D);
  float4 v[8];
#pragma unroll
  for (int i = 0; i < 8; i++) v[i] = inr[c + 32 * i];

  float ss = 0.f;
#pragma unroll
  for (int i = 0; i < 8; i++)
    ss += v[i].x * v[i].x + v[i].y * v[i].y + v[i].z * v[i].z + v[i].w * v[i].w;
#pragma unroll
  for (int m = 16; m >= 1; m >>= 1) ss += __shfl_xor(ss, m, 32);
  const float inv = 32.0f / fmaxf(sqrtf(ss), 1e-12f);  // pre-scale by 32

#pragma unroll
  for (int i = 0; i < 8; i++) {
    const int n0 = fp4e(v[i].x * inv);
    const int n1 = fp4e(v[i].y * inv);
    const int n2 = fp4e(v[i].z * inv);
    const int n3 = fp4e(v[i].w * inv);
    const unsigned short h =
        (unsigned short)(n0 | (n1 << 4) | (n2 << 8) | (n3 << 12));
    const int f = c + 32 * i;  // 2B-group index
    sPk[(f >> 4) * 512 + (((f >> 3) & 1) * 32 + r) * 8 + (f & 7)] = h;
  }
  __syncthreads();

  const int4* sp4 = (const int4*)sPk;
  ((int4*)out)[(size_t)p * 1024 + tid] = sp4[tid];
}

// ============================================================
// Kernel 2: fused MX-fp4 MFMA GEMM + exp epilogue.
// R15 = R11 (best GEMM: 50.0 us, B-in-LDS, no setprio) with ONE
// change: PERSISTENT OPERAND TUPLES. The four fragment operands are
// i32x8 zero-initialized ONCE before the K-loop; each ds_read_b128
// writes only the low i32x4 in place. The upper halves stay zero
// across iterations -> regalloc coalesces the load into the tuple's
// low regs -> the ~64 v_mov hi-zeroing per wave-kt (R11's LD16)
// disappears from the MFMA-feeding instruction stream.
// Regs: acc 64 + tuples 32 + addr ~12 <= 128 @ (256,4). No asm.
// ============================================================
__global__ __launch_bounds__(256, 4) void infonce_gemm(
    const unsigned char* __restrict__ A, const unsigned char* __restrict__ B,
    const int* __restrict__ la, const int* __restrict__ lb,
    float* __restrict__ pos_acc, float* __restrict__ neg_acc) {
  __shared__ __align__(16) unsigned char sA[16384];
  __shared__ __align__(16) unsigned char sB[16384];

  const int tid = threadIdx.x;
  const int lane = tid & 63;
  const int wave = tid >> 6;  // 0..3
  const int wa = wave >> 1;   // 0..1 (A half: 64 rows)
  const int wb = wave & 1;    // 0..1 (B half: 64 cols)

  // grid 4096 = 64 by x 64 bx; bijective XCD rectangle swizzle
  const int bid = blockIdx.x;
  const int xcd = bid & 7;
  const int local = bid >> 3;              // 0..511
  const int by = xcd * 8 + (local & 7);    // 0..63
  const int bx = local >> 3;               // 0..63
  const int row0 = by * 128;
  const int col0 = bx * 128;

  // staging: 4 panels x 4 records per iter; tid covers record
  // sr=(tid>>6)&3, inner (tid&63)*16; panel u unrolled.
  const int sr1k = ((tid >> 6) & 3) * 1024 + (tid & 63) * 16;
  const unsigned char* gA = A + (size_t)by * 65536 + sr1k;
  const unsigned char* gB = B + (size_t)bx * 65536 + sr1k;

  f32x16 acc[2][2] = {};  // [bi][aj]

#define STAGE(kt)                                                   \
  do {                                                              \
    _Pragma("unroll") for (int u = 0; u < 4; u++) {                 \
      async16(gA + (size_t)u * 16384 + (size_t)(kt)*4096,           \
              &sA[u * 4096 + tid * 16]);                            \
      async16(gB + (size_t)u * 16384 + (size_t)(kt)*4096,           \
              &sB[u * 4096 + tid * 16]);                            \
    }                                                               \
  } while (0)

#define MFMA(ci, x_, y_)                                            \
  ci = __builtin_amdgcn_mfma_scale_f32_32x32x64_f8f6f4(             \
      x_, y_, ci, 4, 4, 0, UNIT_SCALE, 0, UNIT_SCALE)

  const int lofs = lane * 16;
  const int aoff0 = (wa * 2 + 0) * 4096 + lofs;  // + sp*1024
  const int aoff1 = (wa * 2 + 1) * 4096 + lofs;
  const int boff0 = (wb * 2 + 0) * 4096 + lofs;
  const int boff1 = (wb * 2 + 1) * 4096 + lofs;

  // persistent operand tuples: hi halves zeroed ONCE, never rewritten
  i32x8 fa0 = {0, 0, 0, 0, 0, 0, 0, 0};
  i32x8 fa1 = {0, 0, 0, 0, 0, 0, 0, 0};
  i32x8 fb0 = {0, 0, 0, 0, 0, 0, 0, 0};
  i32x8 fb1 = {0, 0, 0, 0, 0, 0, 0, 0};

#pragma unroll 1
  for (int kt = 0; kt < 4; ++kt) {
    STAGE(kt);
    __syncthreads();  // tile resident
#pragma unroll
    for (int sp = 0; sp < 4; ++sp) {
      // in-place low-half loads (ds_read_b128 -> tuple lo regs)
      *(i32x4*)&fa0 = *(const i32x4*)(sA + aoff0 + sp * 1024);
      *(i32x4*)&fa1 = *(const i32x4*)(sA + aoff1 + sp * 1024);
      *(i32x4*)&fb0 = *(const i32x4*)(sB + boff0 + sp * 1024);
      *(i32x4*)&fb1 = *(const i32x4*)(sB + boff1 + sp * 1024);
      // swapped operands: lane&31 <- A-row, regs <- B-col
      MFMA(acc[0][0], fb0, fa0);
      MFMA(acc[0][1], fb0, fa1);
      MFMA(acc[1][0], fb1, fa0);
      MFMA(acc[1][1], fb1, fa1);
    }
    __syncthreads();  // reads done before next STAGE overwrites
  }

  // ---- epilogue (R11 verified): lane l31 = A-row, lane-local col sums
  const int l31 = lane & 31;
  const int hi = lane >> 5;
  const int colw = col0 + wb * 64 + 4 * hi;
  const int rowbase = row0 + wa * 64 + l31;

  const int lav0 = la[rowbase];
  const int lav1 = la[rowbase + 32];

  int lbs[2][16];
#pragma unroll
  for (int bi = 0; bi < 2; bi++)
#pragma unroll
    for (int r = 0; r < 16; r++)
      lbs[bi][r] = lb[colw + bi * 32 + (r & 3) + 8 * (r >> 2)];

#pragma unroll
  for (int aj = 0; aj < 2; aj++) {
    const int lav = aj ? lav1 : lav0;
    float sn = 0.f, sp = 0.f;
#pragma unroll
    for (int bi = 0; bi < 2; bi++)
#pragma unroll
      for (int r = 0; r < 16; r++) {
        const float e = exp2f(acc[bi][aj][r] * K2EPI);  // e^(s/T), |s/T|<50
        sn += e;
        sp += (lav == lbs[bi][r]) ? e : 0.f;
      }
    sn += __shfl_xor(sn, 32, 64);
    sp += __shfl_xor(sp, 32, 64);
    if (hi == 0) {
      const int row = rowbase + aj * 32;
      atomicAdd(&neg_acc[row], sn);
      atomicAdd(&pos_acc[row], sp);
    }
  }
}

// ============================================================
// Kernel 3: loss partials -> atomic mean. 8 blocks x 256 thr.
// out[0] zeroed by normalize (stream-ordered).
// ============================================================
__global__ __launch_bounds__(256) void final_reduce(
    const float* __restrict__ pos, const float* __restrict__ neg,
    float* __restrict__ out, int N) {
  const int i = blockIdx.x * 256 + threadIdx.x;  // 0..2047
  const float4 p4 = ((const float4*)pos)[i];
  const float4 n4 = ((const float4*)neg)[i];
  float local = (logf(n4.x) - logf(fmaxf(p4.x, 1e-8f))) +
                (logf(n4.y) - logf(fmaxf(p4.y, 1e-8f))) +
                (logf(n4.z) - logf(fmaxf(p4.z, 1e-8f))) +
                (logf(n4.w) - logf(fmaxf(p4.w, 1e-8f)));
#pragma unroll
  for (int m = 32; m >= 1; m >>= 1) local += __shfl_xor(local, m, 64);
  __shared__ float ws[4];
  const int wv = threadIdx.x >> 6, lane = threadIdx.x & 63;
  if (lane == 0) ws[wv] = local;
  __syncthreads();
  if (threadIdx.x == 0)
    atomicAdd(out, (ws[0] + ws[1] + ws[2] + ws[3]) * (1.0f / (float)N));
}

extern "C" void kernel_launch(void* const* d_in, const int* in_sizes, int n_in,
                              void* d_out, int out_size, void* d_ws, size_t ws_size,
                              hipStream_t stream) {
  const float* fa = (const float*)d_in[0];
  const float* fb = (const float*)d_in[1];
  const int* la = (const int*)d_in[2];
  const int* lb = (const int*)d_in[3];

  const int D = 1024;
  const int N = in_sizes[0] / D;  // 8192
  const int M = in_sizes[1] / D;  // 8192

  unsigned char* nA = (unsigned char*)d_ws;            // 4 MB fp4
  unsigned char* nB = nA + (size_t)N * D / 2;          // 4 MB fp4
  float* pos = (float*)(nB + (size_t)M * D / 2);
  float* neg = pos + N;

  normalize_rows<<<512, 1024, 0, stream>>>(fa, fb, (int*)nA, (int*)nB, pos,
                                           neg, (float*)d_out, N, D);

  infonce_gemm<<<4096, 256, 0, stream>>>(nA, nB, la, lb, pos, neg);

  final_reduce<<<8, 256, 0, stream>>>(pos, neg, (float*)d_out, N);
}